// Round 1
// baseline (336.334 us; speedup 1.0000x reference)
//
#include <hip/hip_runtime.h>
#include <hip/hip_bf16.h>

// ---------- helpers ----------

typedef __attribute__((ext_vector_type(8))) short bf16x8;
typedef __attribute__((ext_vector_type(4))) float f32x4;

#define AS_G(p) ((__attribute__((address_space(1))) void*)(p))
#define AS_L(p) ((__attribute__((address_space(3))) void*)(p))

__device__ __forceinline__ unsigned short f2bf(float f) {
  // round-to-nearest-even bf16 (finite inputs only)
  unsigned int u = __float_as_uint(f);
  unsigned int lsb = (u >> 16) & 1u;
  u += 0x7fffu + lsb;
  return (unsigned short)(u >> 16);
}

__device__ __forceinline__ float bf2f(unsigned short h) {
  return __uint_as_float(((unsigned int)h) << 16);
}

__device__ __forceinline__ void storeC(float* p, float v) { *p = v; }
__device__ __forceinline__ void storeC(unsigned short* p, float v) { *p = f2bf(v); }

__device__ __forceinline__ float toF(float v) { return v; }
__device__ __forceinline__ float toF(unsigned short v) { return bf2f(v); }

// ---------- generic NT GEMM: C[M,N] = A[M,K] * B[N,K]^T (+bias[N]) ----------
// A,B bf16 row-major (K contiguous). 128x128 block tile, BK=32, 256 threads
// (4 waves, each computing a 64x64 quadrant as 4x4 MFMA 16x16x32 tiles).

template <typename OutT, bool HAS_BIAS>
__global__ __launch_bounds__(256) void gemm_nt(
    const unsigned short* __restrict__ A, const unsigned short* __restrict__ B,
    OutT* __restrict__ C, const float* __restrict__ bias,
    int M, int N, int K, long long sA, long long sB, long long sC)
{
  __shared__ unsigned short lA[128 * 32];
  __shared__ unsigned short lB[128 * 32];

  const int t = threadIdx.x;
  const int rowBase = blockIdx.y * 128;
  const int colBase = blockIdx.x * 128;
  A += (long long)blockIdx.z * sA;
  B += (long long)blockIdx.z * sB;
  C += (long long)blockIdx.z * sC;

  const int l = t & 63;
  const int w = t >> 6;
  const int wrow = (w >> 1) * 64;
  const int wcol = (w & 1) * 64;
  const int q = l >> 4;       // lane quad
  const int r16 = l & 15;

  f32x4 acc[4][4] = {};

  // staging: tile is 128 rows x 32 k-elems of bf16 = 8192 B = 512 x 16B chunks.
  // chunk c -> row c>>2, k-offset (c&3)*8 ; LDS flat byte offset c*16
  // (wave-uniform base + lane*16 as required by global_load_lds).
  const int c0 = t;
  const int c1 = t + 256;
  const int a0row = c0 >> 2, a0cc = (c0 & 3) << 3;
  const int a1row = c1 >> 2, a1cc = (c1 & 3) << 3;

  for (int kt = 0; kt < K; kt += 32) {
    __syncthreads();
    __builtin_amdgcn_global_load_lds(AS_G(A + (size_t)(rowBase + a0row) * K + kt + a0cc),
                                     AS_L(lA + c0 * 8), 16, 0, 0);
    __builtin_amdgcn_global_load_lds(AS_G(A + (size_t)(rowBase + a1row) * K + kt + a1cc),
                                     AS_L(lA + c1 * 8), 16, 0, 0);
    __builtin_amdgcn_global_load_lds(AS_G(B + (size_t)(colBase + a0row) * K + kt + a0cc),
                                     AS_L(lB + c0 * 8), 16, 0, 0);
    __builtin_amdgcn_global_load_lds(AS_G(B + (size_t)(colBase + a1row) * K + kt + a1cc),
                                     AS_L(lB + c1 * 8), 16, 0, 0);
    __syncthreads();

    bf16x8 af[4], bfr[4];
#pragma unroll
    for (int i = 0; i < 4; i++)
      af[i] = *(const bf16x8*)(lA + (wrow + i * 16 + r16) * 32 + q * 8);
#pragma unroll
    for (int j = 0; j < 4; j++)
      bfr[j] = *(const bf16x8*)(lB + (wcol + j * 16 + r16) * 32 + q * 8);
#pragma unroll
    for (int i = 0; i < 4; i++)
#pragma unroll
      for (int j = 0; j < 4; j++)
        acc[i][j] = __builtin_amdgcn_mfma_f32_16x16x32_bf16(af[i], bfr[j], acc[i][j], 0, 0, 0);
  }

  // epilogue: C layout row=(lane>>4)*4+r, col=lane&15  (m89/m91 verified)
#pragma unroll
  for (int i = 0; i < 4; i++) {
#pragma unroll
    for (int r = 0; r < 4; r++) {
      int row = rowBase + wrow + i * 16 + q * 4 + r;
#pragma unroll
      for (int j = 0; j < 4; j++) {
        int col = colBase + wcol + j * 16 + r16;
        float v = acc[i][j][r];
        if (HAS_BIAS) v += bias[col];
        storeC(C + (size_t)row * N + col, v);
      }
    }
  }
}

// ---------- fp32 -> bf16 cast (vectorized) ----------

__global__ __launch_bounds__(256) void cast_f32_to_bf16(
    const float* __restrict__ in, unsigned short* __restrict__ out, int n4)
{
  int i = blockIdx.x * 256 + threadIdx.x;
  if (i >= n4) return;
  float4 v = ((const float4*)in)[i];
  ushort4 o;
  o.x = f2bf(v.x); o.y = f2bf(v.y); o.z = f2bf(v.z); o.w = f2bf(v.w);
  ((ushort4*)out)[i] = o;
}

// ---------- transpose (+cast) to bf16: out[C,R] = bf16(in[R,C]) ----------

template <typename InT>
__global__ __launch_bounds__(256) void transpose_to_bf16(
    const InT* __restrict__ in, unsigned short* __restrict__ out, int R, int Cc)
{
  __shared__ float tile[32][33];
  const int bc = blockIdx.x * 32;
  const int br = blockIdx.y * 32;
  const size_t base = (size_t)blockIdx.z * (size_t)R * (size_t)Cc;
  const int tx = threadIdx.x;
  const int ty = threadIdx.y;
#pragma unroll
  for (int i = 0; i < 4; i++) {
    int r = br + ty + i * 8;
    tile[ty + i * 8][tx] = toF(in[base + (size_t)r * Cc + bc + tx]);
  }
  __syncthreads();
#pragma unroll
  for (int i = 0; i < 4; i++) {
    int c = bc + ty + i * 8;
    out[base + (size_t)c * R + br + tx] = f2bf(tile[tx][ty + i * 8]);
  }
}

// ---------- row softmax: P[row,:] = softmax(S[row,:] * scale) as bf16 ----------
// L = 2048 fixed, 256 threads/row, 8 elems/thread.

__global__ __launch_bounds__(256) void softmax_rows(
    const float* __restrict__ S, unsigned short* __restrict__ P, float scale)
{
  const size_t row = blockIdx.x;
  const float* s = S + row * 2048;
  unsigned short* p = P + row * 2048;
  const int t = threadIdx.x;

  float v[8];
  float m = -1e30f;
#pragma unroll
  for (int i = 0; i < 8; i++) {
    v[i] = s[t + i * 256];
    m = fmaxf(m, v[i]);
  }
#pragma unroll
  for (int off = 32; off >= 1; off >>= 1) m = fmaxf(m, __shfl_xor(m, off));
  __shared__ float redm[4];
  if ((t & 63) == 0) redm[t >> 6] = m;
  __syncthreads();
  m = fmaxf(fmaxf(redm[0], redm[1]), fmaxf(redm[2], redm[3]));

  float e[8];
  float sum = 0.f;
#pragma unroll
  for (int i = 0; i < 8; i++) {
    e[i] = __expf((v[i] - m) * scale);
    sum += e[i];
  }
#pragma unroll
  for (int off = 32; off >= 1; off >>= 1) sum += __shfl_xor(sum, off);
  __shared__ float reds[4];
  if ((t & 63) == 0) reds[t >> 6] = sum;
  __syncthreads();
  sum = reds[0] + reds[1] + reds[2] + reds[3];
  float inv = 1.0f / sum;
#pragma unroll
  for (int i = 0; i < 8; i++) p[t + i * 256] = f2bf(e[i] * inv);
}

// ---------- driver ----------

extern "C" void kernel_launch(void* const* d_in, const int* in_sizes, int n_in,
                              void* d_out, int out_size, void* d_ws, size_t ws_size,
                              hipStream_t stream) {
  (void)in_sizes; (void)n_in; (void)out_size;

  const float* x  = (const float*)d_in[0];
  const float* Wq = (const float*)d_in[1];
  const float* bq = (const float*)d_in[2];
  const float* Wk = (const float*)d_in[3];
  const float* bk = (const float*)d_in[4];
  const float* Wv = (const float*)d_in[5];
  const float* bv = (const float*)d_in[6];
  float* out = (float*)d_out;

  const int Nb = 4, L = 2048, D = 1024, H = 1024, O = 1024;
  const int M = Nb * L; // 8192

  char* ws = (char*)d_ws;
  size_t off = 0;
  unsigned short* xb  = (unsigned short*)(ws + off); off += (size_t)M * D * 2;
  unsigned short* qb  = (unsigned short*)(ws + off); off += (size_t)M * H * 2;
  unsigned short* kb  = (unsigned short*)(ws + off); off += (size_t)M * H * 2;
  unsigned short* vb  = (unsigned short*)(ws + off); off += (size_t)M * O * 2;
  unsigned short* vt  = (unsigned short*)(ws + off); off += (size_t)M * O * 2;
  unsigned short* WqT = (unsigned short*)(ws + off); off += (size_t)D * H * 2;
  unsigned short* WkT = (unsigned short*)(ws + off); off += (size_t)D * H * 2;
  unsigned short* WvT = (unsigned short*)(ws + off); off += (size_t)D * O * 2;
  float* S = (float*)(ws + off); off += (size_t)Nb * L * L * 4;
  // P (bf16, 33.5 MB) aliases xb+qb (dead after the QK GEMM; stream-ordered).
  unsigned short* P = (unsigned short*)ws;
  if (ws_size < off) return;  // workspace too small: fail cleanly

  dim3 blk256(256);
  dim3 tblk(32, 8);

  // x -> bf16
  cast_f32_to_bf16<<<(M * D / 4 + 255) / 256, blk256, 0, stream>>>(x, xb, M * D / 4);

  // W transposes (fp32 -> bf16, [D,H] -> [H,D])
  transpose_to_bf16<float><<<dim3(H / 32, D / 32, 1), tblk, 0, stream>>>(Wq, WqT, D, H);
  transpose_to_bf16<float><<<dim3(H / 32, D / 32, 1), tblk, 0, stream>>>(Wk, WkT, D, H);
  transpose_to_bf16<float><<<dim3(O / 32, D / 32, 1), tblk, 0, stream>>>(Wv, WvT, D, O);

  // projections: qb/kb/vb[M,H] = xb[M,D] @ W^T^T + bias
  gemm_nt<unsigned short, true><<<dim3(H / 128, M / 128, 1), blk256, 0, stream>>>(
      xb, WqT, qb, bq, M, H, D, 0, 0, 0);
  gemm_nt<unsigned short, true><<<dim3(H / 128, M / 128, 1), blk256, 0, stream>>>(
      xb, WkT, kb, bk, M, H, D, 0, 0, 0);
  gemm_nt<unsigned short, true><<<dim3(O / 128, M / 128, 1), blk256, 0, stream>>>(
      xb, WvT, vb, bv, M, O, D, 0, 0, 0);

  // v transpose per batch: [L,O] -> [O,L]
  transpose_to_bf16<unsigned short><<<dim3(O / 32, L / 32, Nb), tblk, 0, stream>>>(
      vb, vt, L, O);

  // scores: S[b] = q[b] @ k[b]^T  (raw, scale folded into softmax)
  gemm_nt<float, false><<<dim3(L / 128, L / 128, Nb), blk256, 0, stream>>>(
      qb, kb, S, nullptr, L, L, H,
      (long long)L * H, (long long)L * H, (long long)L * L);

  // softmax rows -> bf16 P
  softmax_rows<<<Nb * L, blk256, 0, stream>>>(S, P, 0.022097086912079608f /* 1/sqrt(2048) */);

  // out[b] = P[b] @ v[b]  (B = v^T, NT form)
  gemm_nt<float, false><<<dim3(O / 128, L / 128, Nb), blk256, 0, stream>>>(
      P, vt, out, nullptr, L, O, L,
      (long long)L * L, (long long)O * L, (long long)L * O);
}

// Round 2
// 314.996 us; speedup vs baseline: 1.0677x; 1.0677x over previous
//
#include <hip/hip_runtime.h>
#include <hip/hip_bf16.h>

// ---------- helpers ----------

typedef __attribute__((ext_vector_type(8))) short bf16x8;
typedef __attribute__((ext_vector_type(4))) float f32x4;

#define AS_G(p) ((__attribute__((address_space(1))) void*)(p))
#define AS_L(p) ((__attribute__((address_space(3))) void*)(p))

__device__ __forceinline__ unsigned short f2bf(float f) {
  unsigned int u = __float_as_uint(f);
  unsigned int lsb = (u >> 16) & 1u;
  u += 0x7fffu + lsb;
  return (unsigned short)(u >> 16);
}

__device__ __forceinline__ float bf2f(unsigned short h) {
  return __uint_as_float(((unsigned int)h) << 16);
}

__device__ __forceinline__ void storeC(float* p, float v) { *p = v; }
__device__ __forceinline__ void storeC(unsigned short* p, float v) { *p = f2bf(v); }

__device__ __forceinline__ float toF(float v) { return v; }
__device__ __forceinline__ float toF(unsigned short v) { return bf2f(v); }

// ---------- generic strided NT GEMM: C = A * B^T (+bias) ----------
// A[m,k] via lda, B[n,k] via ldb, C[m,n] via ldc; z batches via sA/sB/sC.
// 128x128 tile, BK=32, 256 threads = 4 waves x (64x64 as 4x4 MFMA 16x16x32).
// LDS k-slot XOR swizzle: slot s of row r holds k-segment s ^ ((r>>1)&3).
// Staging stays chunk-linear (global_load_lds requires base + lane*16); the
// swizzle is applied on the GLOBAL k-offset at stage time and on the slot
// at read time. Fragment read banks: 16*(r&1) + 4*(q^((r>>1)&3)) -> 2 lanes
// per 4-bank group = 2-way = free (m136), vs 8-way unswizzled.

template <typename OutT, int BIASMODE>
__global__ __launch_bounds__(256) void gemm_nt(
    const unsigned short* __restrict__ A, const unsigned short* __restrict__ B,
    OutT* __restrict__ C,
    const float* __restrict__ b0, const float* __restrict__ b1,
    const float* __restrict__ b2,
    int K, int lda, int ldb, int ldc,
    long long sA, long long sB, long long sC)
{
  __shared__ unsigned short lA[128 * 32];
  __shared__ unsigned short lB[128 * 32];

  const int t = threadIdx.x;
  const int rowBase = blockIdx.y * 128;
  const int colBase = blockIdx.x * 128;
  A += (long long)blockIdx.z * sA;
  B += (long long)blockIdx.z * sB;
  C += (long long)blockIdx.z * sC;

  const int l = t & 63;
  const int w = t >> 6;
  const int wrow = (w >> 1) * 64;
  const int wcol = (w & 1) * 64;
  const int q = l >> 4;
  const int r16 = l & 15;
  const int slot8 = (q ^ ((r16 >> 1) & 3)) << 3;  // swizzled k-slot (elems)

  f32x4 acc[4][4] = {};

  // staging chunks: chunk c (0..511) -> row c>>2, slot c&3; the global
  // k-segment stored there is (c&3) ^ ((c>>3)&3)  [since row>>1 = c>>3].
  const int c0 = t;
  const int c1 = t + 256;
  const int row0 = c0 >> 2, sw0 = (((c0 & 3) ^ ((c0 >> 3) & 3)) << 3);
  const int row1 = c1 >> 2, sw1 = (((c1 & 3) ^ ((c1 >> 3) & 3)) << 3);

  for (int kt = 0; kt < K; kt += 32) {
    __syncthreads();
    __builtin_amdgcn_global_load_lds(AS_G(A + (size_t)(rowBase + row0) * lda + kt + sw0),
                                     AS_L(lA + c0 * 8), 16, 0, 0);
    __builtin_amdgcn_global_load_lds(AS_G(A + (size_t)(rowBase + row1) * lda + kt + sw1),
                                     AS_L(lA + c1 * 8), 16, 0, 0);
    __builtin_amdgcn_global_load_lds(AS_G(B + (size_t)(colBase + row0) * ldb + kt + sw0),
                                     AS_L(lB + c0 * 8), 16, 0, 0);
    __builtin_amdgcn_global_load_lds(AS_G(B + (size_t)(colBase + row1) * ldb + kt + sw1),
                                     AS_L(lB + c1 * 8), 16, 0, 0);
    __syncthreads();

    bf16x8 af[4], bfr[4];
#pragma unroll
    for (int i = 0; i < 4; i++)
      af[i] = *(const bf16x8*)(lA + (wrow + i * 16 + r16) * 32 + slot8);
#pragma unroll
    for (int j = 0; j < 4; j++)
      bfr[j] = *(const bf16x8*)(lB + (wcol + j * 16 + r16) * 32 + slot8);
#pragma unroll
    for (int i = 0; i < 4; i++)
#pragma unroll
      for (int j = 0; j < 4; j++)
        acc[i][j] = __builtin_amdgcn_mfma_f32_16x16x32_bf16(af[i], bfr[j], acc[i][j], 0, 0, 0);
  }

  // epilogue: C layout row=(lane>>4)*4+r, col=lane&15 (m89/m91 verified)
#pragma unroll
  for (int i = 0; i < 4; i++) {
#pragma unroll
    for (int r = 0; r < 4; r++) {
      int row = rowBase + wrow + i * 16 + q * 4 + r;
#pragma unroll
      for (int j = 0; j < 4; j++) {
        int col = colBase + wcol + j * 16 + r16;
        float v = acc[i][j][r];
        if (BIASMODE == 1) v += b0[col];
        if (BIASMODE == 2) {
          int seg = col >> 10;  // wave-uniform per j (tiles are 16-aligned)
          const float* bp = seg == 0 ? b0 : (seg == 1 ? b1 : b2);
          v += bp[col & 1023];
        }
        storeC(C + (size_t)row * ldc + col, v);
      }
    }
  }
}

// ---------- fp32 -> bf16 cast (vectorized) ----------

__global__ __launch_bounds__(256) void cast_f32_to_bf16(
    const float* __restrict__ in, unsigned short* __restrict__ out, int n4)
{
  int i = blockIdx.x * 256 + threadIdx.x;
  if (i >= n4) return;
  float4 v = ((const float4*)in)[i];
  ushort4 o;
  o.x = f2bf(v.x); o.y = f2bf(v.y); o.z = f2bf(v.z); o.w = f2bf(v.w);
  ((ushort4*)out)[i] = o;
}

// ---------- strided transpose (+cast) to bf16 ----------
// out[c, r] = bf16(in[r, c]) ; 32x32 tiles, block (32,8).

template <typename InT>
__global__ __launch_bounds__(256) void transpose_to_bf16(
    const InT* __restrict__ in, unsigned short* __restrict__ out,
    int ld_in, int ld_out, long long sIn, long long sOut)
{
  __shared__ float tile[32][33];
  const int bc = blockIdx.x * 32;
  const int br = blockIdx.y * 32;
  const InT* ip = in + (long long)blockIdx.z * sIn;
  unsigned short* op = out + (long long)blockIdx.z * sOut;
  const int tx = threadIdx.x;
  const int ty = threadIdx.y;
#pragma unroll
  for (int i = 0; i < 4; i++) {
    int r = br + ty + i * 8;
    tile[ty + i * 8][tx] = toF(ip[(size_t)r * ld_in + bc + tx]);
  }
  __syncthreads();
#pragma unroll
  for (int i = 0; i < 4; i++) {
    int c = bc + ty + i * 8;
    op[(size_t)c * ld_out + br + tx] = f2bf(tile[tx][ty + i * 8]);
  }
}

// ---------- row softmax: P[row,:] = softmax(S[row,:] * scale) as bf16 ----------

__global__ __launch_bounds__(256) void softmax_rows(
    const float* __restrict__ S, unsigned short* __restrict__ P, float scale)
{
  const size_t row = blockIdx.x;
  const float* s = S + row * 2048;
  unsigned short* p = P + row * 2048;
  const int t = threadIdx.x;

  float v[8];
  float m = -1e30f;
#pragma unroll
  for (int i = 0; i < 8; i++) {
    v[i] = s[t + i * 256];
    m = fmaxf(m, v[i]);
  }
#pragma unroll
  for (int off = 32; off >= 1; off >>= 1) m = fmaxf(m, __shfl_xor(m, off));
  __shared__ float redm[4];
  if ((t & 63) == 0) redm[t >> 6] = m;
  __syncthreads();
  m = fmaxf(fmaxf(redm[0], redm[1]), fmaxf(redm[2], redm[3]));

  float e[8];
  float sum = 0.f;
#pragma unroll
  for (int i = 0; i < 8; i++) {
    e[i] = __expf((v[i] - m) * scale);
    sum += e[i];
  }
#pragma unroll
  for (int off = 32; off >= 1; off >>= 1) sum += __shfl_xor(sum, off);
  __shared__ float reds[4];
  if ((t & 63) == 0) reds[t >> 6] = sum;
  __syncthreads();
  sum = reds[0] + reds[1] + reds[2] + reds[3];
  float inv = 1.0f / sum;
#pragma unroll
  for (int i = 0; i < 8; i++) p[t + i * 256] = f2bf(e[i] * inv);
}

// ---------- driver ----------

extern "C" void kernel_launch(void* const* d_in, const int* in_sizes, int n_in,
                              void* d_out, int out_size, void* d_ws, size_t ws_size,
                              hipStream_t stream) {
  (void)in_sizes; (void)n_in; (void)out_size;

  const float* x  = (const float*)d_in[0];
  const float* Wq = (const float*)d_in[1];
  const float* bq = (const float*)d_in[2];
  const float* Wk = (const float*)d_in[3];
  const float* bk = (const float*)d_in[4];
  const float* Wv = (const float*)d_in[5];
  const float* bv = (const float*)d_in[6];
  float* out = (float*)d_out;

  const int Nb = 4, L = 2048, D = 1024, H = 1024, O = 1024;
  const int M = Nb * L;      // 8192
  const int NQKV = 3 * H;    // 3072

  char* ws = (char*)d_ws;
  size_t off = 0;
  unsigned short* xb   = (unsigned short*)(ws + off); off += (size_t)M * D * 2;
  unsigned short* qkv  = (unsigned short*)(ws + off); off += (size_t)M * NQKV * 2;
  unsigned short* vt   = (unsigned short*)(ws + off); off += (size_t)M * O * 2;
  unsigned short* WT   = (unsigned short*)(ws + off); off += (size_t)NQKV * D * 2;
  float* S = (float*)(ws + off); off += (size_t)Nb * L * L * 4;
  // P (bf16, 33.5 MB) aliases qkv (dead after vt-transpose + QK GEMM).
  unsigned short* P = qkv;
  if (ws_size < off) return;

  dim3 blk256(256);
  dim3 tblk(32, 8);

  // x -> bf16
  cast_f32_to_bf16<<<(M * D / 4 + 255) / 256, blk256, 0, stream>>>(x, xb, M * D / 4);

  // WT = concat(Wq^T, Wk^T, Wv^T) as bf16 [3072, 1024]
  transpose_to_bf16<float><<<dim3(H / 32, D / 32, 1), tblk, 0, stream>>>(
      Wq, WT, H, D, 0, 0);
  transpose_to_bf16<float><<<dim3(H / 32, D / 32, 1), tblk, 0, stream>>>(
      Wk, WT + (size_t)H * D, H, D, 0, 0);
  transpose_to_bf16<float><<<dim3(O / 32, D / 32, 1), tblk, 0, stream>>>(
      Wv, WT + (size_t)2 * H * D, O, D, 0, 0);

  // fused projections: qkv[M,3072] = xb[M,1024] @ WT^T + bias(seg)
  gemm_nt<unsigned short, 2><<<dim3(NQKV / 128, M / 128, 1), blk256, 0, stream>>>(
      xb, WT, qkv, bq, bk, bv, D, D, D, NQKV, 0, 0, 0);

  // vt[b] = v[b]^T : [O, L] from qkv cols 2048..3071
  transpose_to_bf16<unsigned short><<<dim3(O / 32, L / 32, Nb), tblk, 0, stream>>>(
      qkv + 2 * H, vt, NQKV, L, (long long)L * NQKV, (long long)O * L);

  // scores: S[b] = q[b] @ k[b]^T
  gemm_nt<float, 0><<<dim3(L / 128, L / 128, Nb), blk256, 0, stream>>>(
      qkv, qkv + H, S, nullptr, nullptr, nullptr,
      H, NQKV, NQKV, L,
      (long long)L * NQKV, (long long)L * NQKV, (long long)L * L);

  // softmax rows -> bf16 P (aliases qkv; q/k/v all dead by now)
  softmax_rows<<<Nb * L, blk256, 0, stream>>>(S, P, 0.022097086912079608f);

  // out[b] = P[b] @ v[b] = P[b] @ vt[b]^T
  gemm_nt<float, 0><<<dim3(O / 128, L / 128, Nb), blk256, 0, stream>>>(
      P, vt, out, nullptr, nullptr, nullptr,
      L, L, L, O,
      (long long)L * L, (long long)O * L, (long long)L * O);
}

// Round 4
// 276.536 us; speedup vs baseline: 1.2162x; 1.1391x over previous
//
#include <hip/hip_runtime.h>
#include <hip/hip_bf16.h>

// ---------- helpers ----------

typedef __attribute__((ext_vector_type(8))) short bf16x8;
typedef __attribute__((ext_vector_type(4))) float f32x4;

#define AS_G(p) ((__attribute__((address_space(1))) void*)(p))
#define AS_L(p) ((__attribute__((address_space(3))) void*)(p))

__device__ __forceinline__ unsigned short f2bf(float f) {
  unsigned int u = __float_as_uint(f);
  unsigned int lsb = (u >> 16) & 1u;
  u += 0x7fffu + lsb;
  return (unsigned short)(u >> 16);
}

__device__ __forceinline__ float bf2f(unsigned short h) {
  return __uint_as_float(((unsigned int)h) << 16);
}

// ---------- BK=64 NT GEMM: C = A * B^T ----------
// A[m,k] lda, B[n,k] ldb, bf16, K-contiguous. 128x128 tile, BK=64 (32 KB LDS,
// half the barriers of BK=32), 256 threads = 4 waves x (64x64 = 4x4 MFMA
// 16x16x32). LDS row = 8 chunks of 8 elems (16B); chunk slot s of row r holds
// global k-chunk s ^ (r&7). Fragment read: lanes of one quad spread over all
// 8 slots (2 rows each) -> 2-way bank aliasing = free (m136); round-2's
// analogous swizzle measured exactly 0 SQ_LDS_BANK_CONFLICT.
//
// EPI=0: C fp32 strided (ldc, sC).
// EPI=2: QKV split epilogue: col seg 0 -> qb (+bq), seg 1 -> kb (+bk),
//        seg 2 -> vt TRANSPOSED (+bv) as ushort4 (4 consecutive L-positions
//        per lane, since C-layout rows q*4+r are consecutive).

template <int EPI>
__global__ __launch_bounds__(256) void gemm64(
    const unsigned short* __restrict__ A, const unsigned short* __restrict__ B,
    float* __restrict__ C, long long sA, long long sB, long long sC,
    int K, int lda, int ldb, int ldc,
    unsigned short* __restrict__ qb, unsigned short* __restrict__ kb,
    unsigned short* __restrict__ vt,
    const float* __restrict__ bq, const float* __restrict__ bk_,
    const float* __restrict__ bv)
{
  __shared__ unsigned short lA[128 * 64];
  __shared__ unsigned short lB[128 * 64];

  const int t = threadIdx.x;
  const int rowBase = blockIdx.y * 128;
  const int colBase = blockIdx.x * 128;
  A += (long long)blockIdx.z * sA;
  B += (long long)blockIdx.z * sB;

  const int l = t & 63;
  const int w = t >> 6;
  const int wrow = (w >> 1) * 64;
  const int wcol = (w & 1) * 64;
  const int q = l >> 4;
  const int r16 = l & 15;

  f32x4 acc[4][4] = {};

  // staging: 1024 chunks/matrix; thread t stages chunks t+256u (u=0..3).
  // chunk c: row=c>>3, slot=c&7, global k-chunk = slot ^ (row&7).
  // For c=t+256u: row = (t>>3)+32u, slot = t&7 -> global offset is u-invariant.
  const int r0 = t >> 3;
  const int goff = (((t & 7) ^ (r0 & 7)) << 3);

  for (int kt = 0; kt < K; kt += 64) {
    __syncthreads();
#pragma unroll
    for (int u = 0; u < 4; u++) {
      const int row = r0 + 32 * u;
      __builtin_amdgcn_global_load_lds(AS_G(A + (size_t)(rowBase + row) * lda + kt + goff),
                                       AS_L(lA + (t + 256 * u) * 8), 16, 0, 0);
      __builtin_amdgcn_global_load_lds(AS_G(B + (size_t)(colBase + row) * ldb + kt + goff),
                                       AS_L(lB + (t + 256 * u) * 8), 16, 0, 0);
    }
    __syncthreads();

#pragma unroll
    for (int ks = 0; ks < 2; ks++) {
      bf16x8 af[4], bfr[4];
#pragma unroll
      for (int i = 0; i < 4; i++) {
        const int s = ((ks * 4 + q) ^ (r16 & 7));
        af[i] = *(const bf16x8*)(lA + (wrow + i * 16 + r16) * 64 + s * 8);
      }
#pragma unroll
      for (int j = 0; j < 4; j++) {
        const int s = ((ks * 4 + q) ^ (r16 & 7));
        bfr[j] = *(const bf16x8*)(lB + (wcol + j * 16 + r16) * 64 + s * 8);
      }
#pragma unroll
      for (int i = 0; i < 4; i++)
#pragma unroll
        for (int j = 0; j < 4; j++)
          acc[i][j] = __builtin_amdgcn_mfma_f32_16x16x32_bf16(af[i], bfr[j], acc[i][j], 0, 0, 0);
    }
  }

  // epilogue: C layout row=(lane>>4)*4+r, col=lane&15 (m89/m91 verified)
  if (EPI == 0) {
    C += (long long)blockIdx.z * sC;
#pragma unroll
    for (int i = 0; i < 4; i++) {
#pragma unroll
      for (int r = 0; r < 4; r++) {
        int row = rowBase + wrow + i * 16 + q * 4 + r;
#pragma unroll
        for (int j = 0; j < 4; j++) {
          int col = colBase + wcol + j * 16 + r16;
          C[(size_t)row * ldc + col] = acc[i][j][r];
        }
      }
    }
  } else {
    const int seg = colBase >> 10;  // block-uniform (128 | 1024)
    if (seg < 2) {
      unsigned short* dst = seg ? kb : qb;
      const float* bias = seg ? bk_ : bq;
      const int cb = colBase & 1023;
#pragma unroll
      for (int i = 0; i < 4; i++) {
#pragma unroll
        for (int r = 0; r < 4; r++) {
          int row = rowBase + wrow + i * 16 + q * 4 + r;
#pragma unroll
          for (int j = 0; j < 4; j++) {
            int col = cb + wcol + j * 16 + r16;
            dst[(size_t)row * 1024 + col] = f2bf(acc[i][j][r] + bias[col]);
          }
        }
      }
    } else {
      const int ob = colBase - 2048;
#pragma unroll
      for (int i = 0; i < 4; i++) {
        int posBase = rowBase + wrow + i * 16 + q * 4;
        int b = posBase >> 11;
        int pos = posBase & 2047;
#pragma unroll
        for (int j = 0; j < 4; j++) {
          int o = ob + wcol + j * 16 + r16;
          float bias = bv[o];
          ushort4 pk;
          pk.x = f2bf(acc[i][j][0] + bias);
          pk.y = f2bf(acc[i][j][1] + bias);
          pk.z = f2bf(acc[i][j][2] + bias);
          pk.w = f2bf(acc[i][j][3] + bias);
          *(ushort4*)(vt + ((size_t)((b << 10) + o) * 2048 + pos)) = pk;
        }
      }
    }
  }
}

// ---------- fp32 -> bf16 cast (vectorized) ----------

__global__ __launch_bounds__(256) void cast_f32_to_bf16(
    const float* __restrict__ in, unsigned short* __restrict__ out, int n4)
{
  int i = blockIdx.x * 256 + threadIdx.x;
  if (i >= n4) return;
  float4 v = ((const float4*)in)[i];
  ushort4 o;
  o.x = f2bf(v.x); o.y = f2bf(v.y); o.z = f2bf(v.z); o.w = f2bf(v.w);
  ((ushort4*)out)[i] = o;
}

// ---------- W transpose: WT[z][h, d] = bf16(W_z[d, h]), 1024x1024, z=0..2 ----------

__global__ __launch_bounds__(256) void wtrans(
    const float* __restrict__ Wq, const float* __restrict__ Wk,
    const float* __restrict__ Wv, unsigned short* __restrict__ WT)
{
  __shared__ float tile[32][33];
  const float* in = blockIdx.z == 0 ? Wq : (blockIdx.z == 1 ? Wk : Wv);
  unsigned short* out = WT + (size_t)blockIdx.z * 1024 * 1024;
  const int bc = blockIdx.x * 32;  // h
  const int br = blockIdx.y * 32;  // d
  const int tx = threadIdx.x;
  const int ty = threadIdx.y;
#pragma unroll
  for (int i = 0; i < 4; i++)
    tile[ty + i * 8][tx] = in[(size_t)(br + ty + i * 8) * 1024 + bc + tx];
  __syncthreads();
#pragma unroll
  for (int i = 0; i < 4; i++)
    out[(size_t)(bc + ty + i * 8) * 1024 + br + tx] = f2bf(tile[tx][ty + i * 8]);
}

// ---------- row softmax: P[row,:] = softmax(S[row,:] * scale) as bf16 ----------

__global__ __launch_bounds__(256) void softmax_rows(
    const float* __restrict__ S, unsigned short* __restrict__ P, float scale)
{
  const size_t row = blockIdx.x;
  const float* s = S + row * 2048;
  unsigned short* p = P + row * 2048;
  const int t = threadIdx.x;

  float v[8];
  float m = -1e30f;
#pragma unroll
  for (int i = 0; i < 8; i++) {
    v[i] = s[t + i * 256];
    m = fmaxf(m, v[i]);
  }
#pragma unroll
  for (int off = 32; off >= 1; off >>= 1) m = fmaxf(m, __shfl_xor(m, off));
  __shared__ float redm[4];
  if ((t & 63) == 0) redm[t >> 6] = m;
  __syncthreads();
  m = fmaxf(fmaxf(redm[0], redm[1]), fmaxf(redm[2], redm[3]));

  float e[8];
  float sum = 0.f;
#pragma unroll
  for (int i = 0; i < 8; i++) {
    e[i] = __expf((v[i] - m) * scale);
    sum += e[i];
  }
#pragma unroll
  for (int off = 32; off >= 1; off >>= 1) sum += __shfl_xor(sum, off);
  __shared__ float reds[4];
  if ((t & 63) == 0) reds[t >> 6] = sum;
  __syncthreads();
  sum = reds[0] + reds[1] + reds[2] + reds[3];
  float inv = 1.0f / sum;
#pragma unroll
  for (int i = 0; i < 8; i++) p[t + i * 256] = f2bf(e[i] * inv);
}

// ---------- driver ----------

extern "C" void kernel_launch(void* const* d_in, const int* in_sizes, int n_in,
                              void* d_out, int out_size, void* d_ws, size_t ws_size,
                              hipStream_t stream) {
  (void)in_sizes; (void)n_in; (void)out_size;

  const float* x  = (const float*)d_in[0];
  const float* Wq = (const float*)d_in[1];
  const float* bq = (const float*)d_in[2];
  const float* Wk = (const float*)d_in[3];
  const float* bk = (const float*)d_in[4];
  const float* Wv = (const float*)d_in[5];
  const float* bv = (const float*)d_in[6];
  float* out = (float*)d_out;

  const int Nb = 4, L = 2048, D = 1024, H = 1024, O = 1024;
  const int M = Nb * L;      // 8192
  const int NQKV = 3 * H;    // 3072

  char* ws = (char*)d_ws;
  size_t off = 0;
  unsigned short* xb = (unsigned short*)(ws + off); off += (size_t)M * D * 2;
  unsigned short* qb = (unsigned short*)(ws + off); off += (size_t)M * H * 2;
  unsigned short* kb = (unsigned short*)(ws + off); off += (size_t)M * H * 2;
  unsigned short* vt = (unsigned short*)(ws + off); off += (size_t)M * O * 2;
  unsigned short* WT = (unsigned short*)(ws + off); off += (size_t)NQKV * D * 2;
  float* S = (float*)(ws + off); off += (size_t)Nb * L * L * 4;
  // P (bf16, 33.5 MB) aliases qb+kb (both dead after the QK GEMM).
  unsigned short* P = qb;
  if (ws_size < off) return;

  dim3 blk256(256);

  // x -> bf16
  cast_f32_to_bf16<<<(M * D / 4 + 255) / 256, blk256, 0, stream>>>(x, xb, M * D / 4);

  // WT = concat(Wq^T, Wk^T, Wv^T) as bf16 [3072, 1024] (one launch, z=3)
  wtrans<<<dim3(32, 32, 3), dim3(32, 8), 0, stream>>>(Wq, Wk, Wv, WT);

  // fused projections: q -> qb, k -> kb, v -> vt (transposed), + biases
  gemm64<2><<<dim3(NQKV / 128, M / 128, 1), blk256, 0, stream>>>(
      xb, WT, nullptr, 0, 0, 0, D, D, D, 0, qb, kb, vt, bq, bk, bv);

  // scores: S[b] = q[b] @ k[b]^T
  gemm64<0><<<dim3(L / 128, L / 128, Nb), blk256, 0, stream>>>(
      qb, kb, S, (long long)L * H, (long long)L * H, (long long)L * L,
      H, H, H, L, nullptr, nullptr, nullptr, nullptr, nullptr, nullptr);

  // softmax rows -> bf16 P (aliases qb/kb)
  softmax_rows<<<Nb * L, blk256, 0, stream>>>(S, P, 0.022097086912079608f);

  // out[b] = P[b] @ vt[b]^T
  gemm64<0><<<dim3(O / 128, L / 128, Nb), blk256, 0, stream>>>(
      P, vt, out, (long long)L * L, (long long)O * L, (long long)L * O,
      L, L, L, O, nullptr, nullptr, nullptr, nullptr, nullptr, nullptr);
}

// Round 5
// 271.779 us; speedup vs baseline: 1.2375x; 1.0175x over previous
//
#include <hip/hip_runtime.h>
#include <hip/hip_bf16.h>

// ---------- helpers ----------

typedef __attribute__((ext_vector_type(8))) short bf16x8;
typedef __attribute__((ext_vector_type(4))) float f32x4;

#define AS_G(p) ((__attribute__((address_space(1))) void*)(p))
#define AS_L(p) ((__attribute__((address_space(3))) void*)(p))

__device__ __forceinline__ unsigned short f2bf(float f) {
  unsigned int u = __float_as_uint(f);
  unsigned int lsb = (u >> 16) & 1u;
  u += 0x7fffu + lsb;
  return (unsigned short)(u >> 16);
}

__device__ __forceinline__ float bf2f(unsigned short h) {
  return __uint_as_float(((unsigned int)h) << 16);
}

// ---------- BK=64 NT GEMM: C = A * B^T ----------
// A[m,k] lda, B[n,k] ldb, bf16, K-contiguous. 128x128 tile, BK=64, 256
// threads = 4 waves x (64x64 = 4x4 MFMA 16x16x32). LDS row = 8 chunks of
// 8 elems (16B); slot s of row r holds global k-chunk s ^ (r&7) -> measured
// 0 SQ_LDS_BANK_CONFLICT (round 2/4).
//
// EPI=1: QK epilogue. P' = bf16(exp(acc*scale)) (unnormalized softmax
//        numerator; no max-subtract needed: |acc*scale| <= ~1.5 by
//        construction), plus fp32 atomic row-sum accumulation into rsum.
// EPI=2: QKV projection split epilogue: col seg 0 -> qb (+bq), seg 1 -> kb
//        (+bk), seg 2 -> vt TRANSPOSED (+bv) as ushort4.
// EPI=3: PV epilogue: out fp32 = acc / rsum[row].

template <int EPI>
__global__ __launch_bounds__(256) void gemm64(
    const unsigned short* __restrict__ A, const unsigned short* __restrict__ B,
    float* __restrict__ Cf, long long sA, long long sB, long long sC,
    int K, int lda, int ldb, int ldc,
    unsigned short* __restrict__ u0, unsigned short* __restrict__ u1,
    unsigned short* __restrict__ u2,
    const float* __restrict__ f0, const float* __restrict__ f1,
    const float* __restrict__ f2,
    float* __restrict__ rsum, float scale)
{
  __shared__ unsigned short lA[128 * 64];
  __shared__ unsigned short lB[128 * 64];

  const int t = threadIdx.x;
  const int rowBase = blockIdx.y * 128;
  const int colBase = blockIdx.x * 128;
  A += (long long)blockIdx.z * sA;
  B += (long long)blockIdx.z * sB;

  const int l = t & 63;
  const int w = t >> 6;
  const int wrow = (w >> 1) * 64;
  const int wcol = (w & 1) * 64;
  const int q = l >> 4;
  const int r16 = l & 15;

  f32x4 acc[4][4] = {};

  // staging: 1024 chunks/matrix; thread t stages chunks t+256u (u=0..3).
  // chunk c: row=c>>3, slot=c&7, global k-chunk = slot ^ (row&7).
  const int r0 = t >> 3;
  const int goff = (((t & 7) ^ (r0 & 7)) << 3);

  for (int kt = 0; kt < K; kt += 64) {
    __syncthreads();
#pragma unroll
    for (int u = 0; u < 4; u++) {
      const int row = r0 + 32 * u;
      __builtin_amdgcn_global_load_lds(AS_G(A + (size_t)(rowBase + row) * lda + kt + goff),
                                       AS_L(lA + (t + 256 * u) * 8), 16, 0, 0);
      __builtin_amdgcn_global_load_lds(AS_G(B + (size_t)(colBase + row) * ldb + kt + goff),
                                       AS_L(lB + (t + 256 * u) * 8), 16, 0, 0);
    }
    __syncthreads();

#pragma unroll
    for (int ks = 0; ks < 2; ks++) {
      bf16x8 af[4], bfr[4];
#pragma unroll
      for (int i = 0; i < 4; i++) {
        const int s = ((ks * 4 + q) ^ (r16 & 7));
        af[i] = *(const bf16x8*)(lA + (wrow + i * 16 + r16) * 64 + s * 8);
      }
#pragma unroll
      for (int j = 0; j < 4; j++) {
        const int s = ((ks * 4 + q) ^ (r16 & 7));
        bfr[j] = *(const bf16x8*)(lB + (wcol + j * 16 + r16) * 64 + s * 8);
      }
#pragma unroll
      for (int i = 0; i < 4; i++)
#pragma unroll
        for (int j = 0; j < 4; j++)
          acc[i][j] = __builtin_amdgcn_mfma_f32_16x16x32_bf16(af[i], bfr[j], acc[i][j], 0, 0, 0);
    }
  }

  // epilogues: C layout row=(lane>>4)*4+r, col=lane&15 (m89/m91 verified)
  if (EPI == 1) {
    unsigned short* p16 = u0 + (long long)blockIdx.z * sC;
    float* rs = rsum + (long long)blockIdx.z * 2048;
#pragma unroll
    for (int i = 0; i < 4; i++) {
#pragma unroll
      for (int r = 0; r < 4; r++) {
        int row = rowBase + wrow + i * 16 + q * 4 + r;
        float rowpart = 0.f;
#pragma unroll
        for (int j = 0; j < 4; j++) {
          int col = colBase + wcol + j * 16 + r16;
          float e = __expf(acc[i][j][r] * scale);
          p16[(size_t)row * ldc + col] = f2bf(e);
          rowpart += e;
        }
        // reduce across the 16 lanes of the quad (same row)
#pragma unroll
        for (int m = 1; m < 16; m <<= 1) rowpart += __shfl_xor(rowpart, m);
        if (r16 == 0) atomicAdd(rs + row, rowpart);
      }
    }
  } else if (EPI == 2) {
    const int seg = colBase >> 10;  // block-uniform
    if (seg < 2) {
      unsigned short* dst = seg ? u1 : u0;
      const float* bias = seg ? f1 : f0;
      const int cb = colBase & 1023;
#pragma unroll
      for (int i = 0; i < 4; i++) {
#pragma unroll
        for (int r = 0; r < 4; r++) {
          int row = rowBase + wrow + i * 16 + q * 4 + r;
#pragma unroll
          for (int j = 0; j < 4; j++) {
            int col = cb + wcol + j * 16 + r16;
            dst[(size_t)row * 1024 + col] = f2bf(acc[i][j][r] + bias[col]);
          }
        }
      }
    } else {
      const int ob = colBase - 2048;
#pragma unroll
      for (int i = 0; i < 4; i++) {
        int posBase = rowBase + wrow + i * 16 + q * 4;
        int b = posBase >> 11;
        int pos = posBase & 2047;
#pragma unroll
        for (int j = 0; j < 4; j++) {
          int o = ob + wcol + j * 16 + r16;
          float bias = f2[o];
          ushort4 pk;
          pk.x = f2bf(acc[i][j][0] + bias);
          pk.y = f2bf(acc[i][j][1] + bias);
          pk.z = f2bf(acc[i][j][2] + bias);
          pk.w = f2bf(acc[i][j][3] + bias);
          *(ushort4*)(u2 + ((size_t)((b << 10) + o) * 2048 + pos)) = pk;
        }
      }
    }
  } else {  // EPI == 3
    float* C = Cf + (long long)blockIdx.z * sC;
    const float* rs = rsum + (long long)blockIdx.z * 2048;
#pragma unroll
    for (int i = 0; i < 4; i++) {
#pragma unroll
      for (int r = 0; r < 4; r++) {
        int row = rowBase + wrow + i * 16 + q * 4 + r;
        float inv = 1.0f / rs[row];
#pragma unroll
        for (int j = 0; j < 4; j++) {
          int col = colBase + wcol + j * 16 + r16;
          C[(size_t)row * ldc + col] = acc[i][j][r] * inv;
        }
      }
    }
  }
}

// ---------- fp32 -> bf16 cast (vectorized) + rsum zero-fill ----------

__global__ __launch_bounds__(256) void cast_f32_to_bf16(
    const float* __restrict__ in, unsigned short* __restrict__ out, int n4,
    float* __restrict__ rzero, int nz4)
{
  int i = blockIdx.x * 256 + threadIdx.x;
  if (i < nz4) ((float4*)rzero)[i] = make_float4(0.f, 0.f, 0.f, 0.f);
  if (i >= n4) return;
  float4 v = ((const float4*)in)[i];
  ushort4 o;
  o.x = f2bf(v.x); o.y = f2bf(v.y); o.z = f2bf(v.z); o.w = f2bf(v.w);
  ((ushort4*)out)[i] = o;
}

// ---------- W transpose: WT[z][h, d] = bf16(W_z[d, h]), 1024x1024, z=0..2 ----------

__global__ __launch_bounds__(256) void wtrans(
    const float* __restrict__ Wq, const float* __restrict__ Wk,
    const float* __restrict__ Wv, unsigned short* __restrict__ WT)
{
  __shared__ float tile[32][33];
  const float* in = blockIdx.z == 0 ? Wq : (blockIdx.z == 1 ? Wk : Wv);
  unsigned short* out = WT + (size_t)blockIdx.z * 1024 * 1024;
  const int bc = blockIdx.x * 32;  // h
  const int br = blockIdx.y * 32;  // d
  const int tx = threadIdx.x;
  const int ty = threadIdx.y;
#pragma unroll
  for (int i = 0; i < 4; i++)
    tile[ty + i * 8][tx] = in[(size_t)(br + ty + i * 8) * 1024 + bc + tx];
  __syncthreads();
#pragma unroll
  for (int i = 0; i < 4; i++)
    out[(size_t)(bc + ty + i * 8) * 1024 + br + tx] = f2bf(tile[tx][ty + i * 8]);
}

// ---------- driver ----------

extern "C" void kernel_launch(void* const* d_in, const int* in_sizes, int n_in,
                              void* d_out, int out_size, void* d_ws, size_t ws_size,
                              hipStream_t stream) {
  (void)in_sizes; (void)n_in; (void)out_size;

  const float* x  = (const float*)d_in[0];
  const float* Wq = (const float*)d_in[1];
  const float* bq = (const float*)d_in[2];
  const float* Wk = (const float*)d_in[3];
  const float* bk = (const float*)d_in[4];
  const float* Wv = (const float*)d_in[5];
  const float* bv = (const float*)d_in[6];
  float* out = (float*)d_out;

  const int Nb = 4, L = 2048, D = 1024, H = 1024, O = 1024;
  const int M = Nb * L;      // 8192
  const int NQKV = 3 * H;    // 3072

  char* ws = (char*)d_ws;
  size_t off = 0;
  unsigned short* xb = (unsigned short*)(ws + off); off += (size_t)M * D * 2;
  unsigned short* qb = (unsigned short*)(ws + off); off += (size_t)M * H * 2;
  unsigned short* kb = (unsigned short*)(ws + off); off += (size_t)M * H * 2;
  unsigned short* vt = (unsigned short*)(ws + off); off += (size_t)M * O * 2;
  unsigned short* WT = (unsigned short*)(ws + off); off += (size_t)NQKV * D * 2;
  unsigned short* P  = (unsigned short*)(ws + off); off += (size_t)Nb * L * L * 2;
  float* rsum = (float*)(ws + off); off += (size_t)Nb * L * 4;
  if (ws_size < off) return;

  dim3 blk256(256);

  // x -> bf16, and zero the row-sum accumulator (ws is poisoned every call)
  cast_f32_to_bf16<<<(M * D / 4 + 255) / 256, blk256, 0, stream>>>(
      x, xb, M * D / 4, rsum, Nb * L / 4);

  // WT = concat(Wq^T, Wk^T, Wv^T) as bf16 [3072, 1024] (one launch, z=3)
  wtrans<<<dim3(32, 32, 3), dim3(32, 8), 0, stream>>>(Wq, Wk, Wv, WT);

  // fused projections: q -> qb, k -> kb, v -> vt (transposed), + biases
  gemm64<2><<<dim3(NQKV / 128, M / 128, 1), blk256, 0, stream>>>(
      xb, WT, nullptr, 0, 0, 0, D, D, D, 0,
      qb, kb, vt, bq, bk, bv, nullptr, 0.f);

  // QK + exp + row-sum atomics: P'[b] = exp(q k^T * scale), rsum[b][l] = row sums
  gemm64<1><<<dim3(L / 128, L / 128, Nb), blk256, 0, stream>>>(
      qb, kb, nullptr, (long long)L * H, (long long)L * H, (long long)L * L,
      H, H, H, L,
      P, nullptr, nullptr, nullptr, nullptr, nullptr,
      rsum, 0.022097086912079608f /* 1/sqrt(2048) */);

  // out[b] = (P'[b] @ vt[b]^T) / rsum
  gemm64<3><<<dim3(O / 128, L / 128, Nb), blk256, 0, stream>>>(
      P, vt, out, (long long)L * L, (long long)O * L, (long long)L * O,
      L, L, L, O,
      nullptr, nullptr, nullptr, nullptr, nullptr, nullptr,
      rsum, 0.f);
}